// Round 6
// baseline (408.445 us; speedup 1.0000x reference)
//
#include <hip/hip_runtime.h>
#include <stdint.h>
#include <stddef.h>

typedef __attribute__((ext_vector_type(8))) short short8;
typedef __attribute__((ext_vector_type(4))) float float4v;

#define T_SEQ 2048
#define D_MODEL 1024
#define NH 16
#define HD 64

static __device__ __forceinline__ unsigned short f2bf(float f) {
  unsigned u = __builtin_bit_cast(unsigned, f);
  u += 0x7fffu + ((u >> 16) & 1u);
  return (unsigned short)(u >> 16);
}
static __device__ __forceinline__ float bf2f(unsigned short h) {
  unsigned u = ((unsigned)h) << 16;
  return __builtin_bit_cast(float, u);
}
static __device__ __forceinline__ float4v mfma16(short8 a, short8 b, float4v c) {
  return __builtin_amdgcn_mfma_f32_16x16x32_bf16(a, b, c, 0, 0, 0);
}
// fp32 -> 3 bf16 terms (sum reproduces f to ~2^-27 rel)
static __device__ __forceinline__ void split3(float f, unsigned short& h0,
                                              unsigned short& h1, unsigned short& h2) {
  h0 = f2bf(f);
  float r1 = f - bf2f(h0);
  h1 = f2bf(r1);
  float r2 = r1 - bf2f(h1);
  h2 = f2bf(r2);
}
// fp32 -> 2 bf16 terms (~2^-18 rel)
static __device__ __forceinline__ void split2(float f, unsigned short& h0, unsigned short& h1) {
  h0 = f2bf(f);
  h1 = f2bf(f - bf2f(h0));
}

// async global->LDS, 16 B per lane (global_load_lds_dwordx4); guarded fallback
static __device__ __forceinline__ void stage16(const unsigned short* g, unsigned short* l) {
#if __has_builtin(__builtin_amdgcn_global_load_lds)
  __builtin_amdgcn_global_load_lds(
      (const __attribute__((address_space(1))) unsigned int*)g,
      (__attribute__((address_space(3))) unsigned int*)l, 16, 0, 0);
#else
  *(short8*)l = *(const short8*)g;
#endif
}

// ---------------- prep: eta tables + LayerNorm split3 + attn_w split3 ----------------
__global__ __launch_bounds__(256) void prep_kernel(
    const float* x, const float* wgt, const float* attn_w, const float* theta,
    unsigned short* y0, unsigned short* y1, unsigned short* y2,
    unsigned short* W0, unsigned short* W1, unsigned short* W2,
    float* E, float* Einv) {
  __shared__ float rs[4], rq[4];
  int bx = blockIdx.x;
  int tid = threadIdx.x;
  if (bx < 4096) {                       // ---- LayerNorm rows ----
    int row = bx;
    const float* xr = x + (size_t)row * D_MODEL;
    float v[4];
    float sum = 0.f, ssq = 0.f;
    for (int it = 0; it < 4; ++it) {
      float f = xr[tid + 256 * it];
      v[it] = f;
      sum += f; ssq += f * f;
    }
    for (int off = 32; off >= 1; off >>= 1) {
      sum += __shfl_xor(sum, off, 64);
      ssq += __shfl_xor(ssq, off, 64);
    }
    int w = tid >> 6;
    if ((tid & 63) == 0) { rs[w] = sum; rq[w] = ssq; }
    __syncthreads();
    sum = rs[0] + rs[1] + rs[2] + rs[3];
    ssq = rq[0] + rq[1] + rq[2] + rq[3];
    float mu = sum * (1.0f / D_MODEL);
    float var = ssq * (1.0f / D_MODEL) - mu * mu;
    float rstd = rsqrtf(var + 1e-5f);
    for (int it = 0; it < 4; ++it) {
      int d = tid + 256 * it;
      float y = (v[it] - mu) * rstd * wgt[d];
      unsigned short h0, h1, h2;
      split3(y, h0, h1, h2);
      size_t o = (size_t)row * D_MODEL + d;
      y0[o] = h0; y1[o] = h1; y2[o] = h2;
    }
  } else if (bx < 5632) {                // ---- attn_w split3 ----
    size_t base = ((size_t)(bx - 4096) * 256 + tid) * 8;
    int row = (int)(base >> 10);
    short8 a, b, c;
    for (int j = 0; j < 8; ++j) {
      unsigned short h0, h1, h2;
      split3(attn_w[base + j], h0, h1, h2);
      a[j] = (short)h0; b[j] = (short)h1; c[j] = (short)h2;
    }
    *(short8*)(W0 + base) = a;
    *(short8*)(W1 + base) = b;
    if (row < 2048) *(short8*)(W2 + base) = c;
  } else {                               // ---- eta tables ----
    int i = (bx - 5632) * 256 + tid;
    if (i < T_SEQ) {
      float th = theta[0];
      float h = log1pf(expf(th));
      float t = 1.0f + h * (float)i;
      float eta = 3.0f * logf(t);
      eta = fminf(fmaxf(eta, -50.0f), 50.0f);
      E[i] = expf(eta);
      Einv[i] = expf(-eta);
    }
  }
}

// ---------------- proj_w (fp32) -> split2 ----------------
__global__ __launch_bounds__(256) void conv_pw(const float* src, unsigned short* P0,
                                               unsigned short* P1) {
  size_t base = ((size_t)blockIdx.x * 256 + threadIdx.x) * 8;
  short8 a, b;
  for (int j = 0; j < 8; ++j) {
    unsigned short h0, h1;
    split2(src[base + j], h0, h1);
    a[j] = (short)h0; b[j] = (short)h1;
  }
  *(short8*)(P0 + base) = a;
  *(short8*)(P1 + base) = b;
}

// =====================================================================
// QKV GEMM — BK=32, 3-buffer LDS ring, ONE 16-MFMA phase per k-tile.
// (round-5: 160 µs, MfmaUtil 35.5%; LDS-throughput-bound — kept as-is)
// =====================================================================

#define RD_A(BUF, MF)                                                           \
  (*(const short8*)(lds_u + (BUF) * 12288 + (wm * 64 + (MF) * 16 + ln) * 32 +   \
                    slot8))
#define RD_B(BUF, NF)                                                           \
  (*(const short8*)(lds_u + (BUF) * 12288 + 8192 +                              \
                    (wn * 64 + (NF) * 16 + ln) * 32 + slot8))

#define STG(BUF, AP, BP, KI)                                                    \
  do {                                                                          \
    const unsigned short* ga = (AP) + (size_t)(m0 + srow) * 1024 + (KI) + kswz8; \
    stage16(ga, lds_u + (BUF) * 12288 + tid * 8);                               \
    stage16(ga + 128 * 1024, lds_u + (BUF) * 12288 + 4096 + tid * 8);           \
    stage16((BP) + (size_t)(brow0 + srow) * 1024 + (KI) + kswz8,                \
            lds_u + (BUF) * 12288 + 8192 + tid * 8);                            \
  } while (0)

#define ASEL(tb) ((tb) == 5 ? y2 : (((tb) & 1) ? y1 : y0))
#define BSEL(tb) (isV ? ((tb) < 2 ? W0 : W1)                                    \
                      : ((tb) < 2 ? W0 : ((tb) < 4 ? W1 : ((tb) == 4 ? W2 : W0))))

#define SBAR __builtin_amdgcn_s_barrier()
#define SCHED0 __builtin_amdgcn_sched_barrier(0)

#define PHASE(BUF, PBUF)                                                        \
  {                                                                             \
    short8 a0 = RD_A(BUF, 0), a1 = RD_A(BUF, 1);                                \
    short8 a2 = RD_A(BUF, 2), a3 = RD_A(BUF, 3);                                \
    short8 b0 = RD_B(BUF, 0), b1 = RD_B(BUF, 1);                                \
    short8 b2 = RD_B(BUF, 2), b3 = RD_B(BUF, 3);                                \
    bool pref = (t + 2 < NKT);                                                  \
    if (pref) {                                                                 \
      int tt = t + 2, tb = tt >> 5, ki = (tt & 31) << 5;                        \
      const unsigned short* Ap = ASEL(tb);                                      \
      const unsigned short* Bp = BSEL(tb);                                      \
      STG(PBUF, Ap, Bp, ki);                                                    \
    }                                                                           \
    SCHED0; SBAR;                                                               \
    asm volatile("s_waitcnt lgkmcnt(0)" ::: "memory");                          \
    SCHED0;                                                                     \
    __builtin_amdgcn_s_setprio(1);                                              \
    acc[0][0] = mfma16(a0, b0, acc[0][0]);                                      \
    acc[0][1] = mfma16(a0, b1, acc[0][1]);                                      \
    acc[0][2] = mfma16(a0, b2, acc[0][2]);                                      \
    acc[0][3] = mfma16(a0, b3, acc[0][3]);                                      \
    acc[1][0] = mfma16(a1, b0, acc[1][0]);                                      \
    acc[1][1] = mfma16(a1, b1, acc[1][1]);                                      \
    acc[1][2] = mfma16(a1, b2, acc[1][2]);                                      \
    acc[1][3] = mfma16(a1, b3, acc[1][3]);                                      \
    acc[2][0] = mfma16(a2, b0, acc[2][0]);                                      \
    acc[2][1] = mfma16(a2, b1, acc[2][1]);                                      \
    acc[2][2] = mfma16(a2, b2, acc[2][2]);                                      \
    acc[2][3] = mfma16(a2, b3, acc[2][3]);                                      \
    acc[3][0] = mfma16(a3, b0, acc[3][0]);                                      \
    acc[3][1] = mfma16(a3, b1, acc[3][1]);                                      \
    acc[3][2] = mfma16(a3, b2, acc[3][2]);                                      \
    acc[3][3] = mfma16(a3, b3, acc[3][3]);                                      \
    __builtin_amdgcn_s_setprio(0);                                              \
    SCHED0;                                                                     \
    if (pref) { asm volatile("s_waitcnt vmcnt(3)" ::: "memory"); }              \
    else      { asm volatile("s_waitcnt vmcnt(0)" ::: "memory"); }              \
    SBAR;                                                                       \
    ++t;                                                                        \
  }

__global__ __launch_bounds__(512, 4) void qkv_ring(
    const unsigned short* __restrict__ y0, const unsigned short* __restrict__ y1,
    const unsigned short* __restrict__ y2, const unsigned short* __restrict__ W0,
    const unsigned short* __restrict__ W1, const unsigned short* __restrict__ W2,
    const float* __restrict__ E, const float* __restrict__ Einv,
    float* __restrict__ Qf, unsigned short* __restrict__ K0,
    unsigned short* __restrict__ K1, unsigned short* __restrict__ K2,
    unsigned short* __restrict__ VbT) {
  extern __shared__ unsigned short lds_u[];  // 36864 ushorts = 72 KB
  int tid = threadIdx.x;
  int w = tid >> 6, lane = tid & 63, q4 = lane >> 4, ln = lane & 15;
  int wm = w >> 1, wn = w & 1;                    // wave grid 4x2, 64x64 each
  int slot8 = (q4 ^ ((ln >> 1) & 3)) * 8;         // HW-verified read swizzle
  int srow = tid >> 2;
  int kswz8 = ((tid & 3) ^ ((srow >> 1) & 3)) * 8;  // inverse source swizzle

  // grid: QK tiles first (bid<256), V tiles last; XCD swizzle (same-by adjacency)
  int bid = blockIdx.x, bx, by;
  if (bid < 256) {
    int wg = ((bid & 7) << 5) | (bid >> 3);
    by = wg >> 4; bx = wg & 15;
  } else {
    int vid = bid - 256;
    int wg = ((vid & 7) << 4) | (vid >> 3);
    by = wg >> 3; bx = 16 + (wg & 7);
  }
  int m0 = by * 256;
  bool isV = (bx >= 16);
  int NKT = isV ? 96 : 192;
  int brow0 = isV ? (2048 + (bx - 16) * 128) : bx * 128;

  float4v zero = {0.f, 0.f, 0.f, 0.f};
  float4v acc[4][4];
#pragma unroll
  for (int mf = 0; mf < 4; ++mf)
#pragma unroll
    for (int nf = 0; nf < 4; ++nf) acc[mf][nf] = zero;

  // prologue: stage tiles 0,1 into bufs 0,1 (6 loads); wait tile0 -> vmcnt(3)
  {
    const unsigned short* Ap = ASEL(0);
    const unsigned short* Bp = BSEL(0);
    STG(0, Ap, Bp, 0);
    STG(1, Ap, Bp, 32);
  }
  asm volatile("s_waitcnt vmcnt(3)" ::: "memory");
  SBAR;

  int t = 0;
  int nit = NKT / 3;
  for (int it = 0; it < nit; ++it) {
    PHASE(0, 2)
    PHASE(1, 0)
    PHASE(2, 1)
  }

  // ---------------- epilogue (loads drained: tail phases waited vmcnt(0)) ----
  int bi = m0 >> 11, m0g = m0 & 2047;
  if (bx < 8) {
    // Q: scale by E[t]*0.125*log2e, fp32, [bh][t][64]; two passes via LDS
    float* Ql = (float*)lds_u;  // [256][64]
    for (int g = 0; g < 2; ++g) {
      if (wn == g) {
#pragma unroll
        for (int mf = 0; mf < 4; ++mf)
#pragma unroll
          for (int nf = 0; nf < 4; ++nf)
#pragma unroll
            for (int r = 0; r < 4; ++r) {
              int rl = wm * 64 + mf * 16 + q4 * 4 + r;
              int tg = m0g + rl;
              Ql[rl * 64 + nf * 16 + ln] = acc[mf][nf][r] * (E[tg] * 0.1803368801f);
            }
      }
      __syncthreads();
      int h = bx * 2 + g;
      float* dst = Qf + ((size_t)(bi * NH + h) * T_SEQ + m0g) * HD;
      for (int itc = 0; itc < 8; ++itc) {
        int idx = itc * 512 + tid;
        *(float4v*)(dst + idx * 4) = *(const float4v*)(Ql + idx * 4);
      }
      __syncthreads();
    }
  } else if (bx < 16) {
    // K: scale by Einv[t], split3, [bh][t][64] x3; four (g,half) passes via LDS
    unsigned short* Kl = lds_u;  // [3][128][64] = 48 KB
    for (int g = 0; g < 2; ++g)
      for (int half = 0; half < 2; ++half) {
        if (wn == g && (wm >> 1) == half) {
#pragma unroll
          for (int mf = 0; mf < 4; ++mf)
#pragma unroll
            for (int nf = 0; nf < 4; ++nf)
#pragma unroll
              for (int r = 0; r < 4; ++r) {
                int rlh = (wm & 1) * 64 + mf * 16 + q4 * 4 + r;
                int tg = m0g + half * 128 + rlh;
                unsigned short h0, h1, h2;
                split3(acc[mf][nf][r] * Einv[tg], h0, h1, h2);
                int o = rlh * 64 + nf * 16 + ln;
                Kl[o] = h0; Kl[8192 + o] = h1; Kl[16384 + o] = h2;
              }
        }
        __syncthreads();
        int h = (bx - 8) * 2 + g;
        size_t base = ((size_t)(bi * NH + h) * T_SEQ + m0g + half * 128) * HD;
        for (int itc = 0; itc < 2; ++itc) {
          int idx = itc * 512 + tid;
          *(short8*)(K0 + base + idx * 8) = *(const short8*)(Kl + idx * 8);
          *(short8*)(K1 + base + idx * 8) = *(const short8*)(Kl + 8192 + idx * 8);
          *(short8*)(K2 + base + idx * 8) = *(const short8*)(Kl + 16384 + idx * 8);
        }
        __syncthreads();
      }
  } else {
    // V: bf16 truncate, transposed [bh][d][t]; two passes via LDS
    unsigned short* Vl = lds_u;  // [64][256] = 32 KB
    for (int g = 0; g < 2; ++g) {
      if (wn == g) {
#pragma unroll
        for (int mf = 0; mf < 4; ++mf)
#pragma unroll
          for (int nf = 0; nf < 4; ++nf)
#pragma unroll
            for (int r = 0; r < 4; ++r) {
              int rl = wm * 64 + mf * 16 + q4 * 4 + r;
              int d = nf * 16 + ln;
              Vl[d * 256 + rl] = f2bf(acc[mf][nf][r]);
            }
      }
      __syncthreads();
      int h = (bx - 16) * 2 + g;
      unsigned short* dst = VbT + (size_t)(bi * NH + h) * HD * T_SEQ + m0g;
      for (int itc = 0; itc < 4; ++itc) {
        int idx = itc * 512 + tid;
        int d = idx >> 5, c = idx & 31;
        *(short8*)(dst + (size_t)d * T_SEQ + c * 8) = *(const short8*)(Vl + d * 256 + c * 8);
      }
      __syncthreads();
    }
  }
}
#undef RD_A
#undef RD_B
#undef STG
#undef ASEL
#undef BSEL
#undef PHASE
#undef SBAR
#undef SCHED0

// ---------------- fused causal attention (round-6: 32 q-rows/wave) ----------------
// LDS-read amortization: each wave owns TWO 16-row m-fragments (32 q-rows), so
// the block covers a 128-row q-tile with 4 waves. K-term fragments are loaded
// ONCE per (c,ks) and feed both m-frags (24 ds_reads -> 192 QK MFMA per wave
// per step vs round-5's 24 reads -> 48 MFMA). Grid: 512 single-tile blocks,
// bh in low 5 bits (XCD-local KV stream), tile u<8?u:23-u so light tiles finish
// round 1 first and pick up the heaviest round-2 tiles (anti-correlated sums).
// Plds reused per m-frag (wave-local ordering only) -> LDS stays 73.2 KB,
// 2 blocks/CU. Per-element math identical to round-5 (same 64-col step order).
#define ATTN_STAGE(BUF, J0)                                                   \
  for (int i_ = 0; i_ < 2; ++i_) {                                            \
    size_t go_ = (size_t)((J0) + srow + i_ * 32) * 64 + scd * 8;              \
    int lo_ = tid * 8 + i_ * 2048;                                            \
    stage16(Kb0 + go_, &Ks[BUF][0][lo_]);                                     \
    stage16(Kb1 + go_, &Ks[BUF][1][lo_]);                                     \
    stage16(Kb2 + go_, &Ks[BUF][2][lo_]);                                     \
    stage16(Vb + (size_t)(srow + i_ * 32) * T_SEQ + (J0) + scd * 8,           \
            &Vs[BUF][lo_]);                                                   \
  }

#define ATTN_STEP(JT, DIAG)                                                   \
  {                                                                           \
    const int cur_ = (JT) & 1;                                                \
    float p[2][4][4];                                                         \
    for (int c = 0; c < 4; ++c) {                                             \
      float4v s0 = zero, s1 = zero;                                           \
      for (int ks = 0; ks < 2; ++ks) {                                        \
        int koff = ((c * 16 + ln) * 8 + ((ks * 4 + q4) ^ swz)) * 8;           \
        short8 k0v = *(const short8*)&Ks[cur_][0][koff];                      \
        short8 k1v = *(const short8*)&Ks[cur_][1][koff];                      \
        short8 k2v = *(const short8*)&Ks[cur_][2][koff];                      \
        s0 = mfma16(qa[0][ks][0], k0v, s0);                                   \
        s0 = mfma16(qa[0][ks][1], k0v, s0);                                   \
        s0 = mfma16(qa[0][ks][0], k1v, s0);                                   \
        s0 = mfma16(qa[0][ks][1], k1v, s0);                                   \
        s0 = mfma16(qa[0][ks][0], k2v, s0);                                   \
        s0 = mfma16(qa[0][ks][2], k0v, s0);                                   \
        s1 = mfma16(qa[1][ks][0], k0v, s1);                                   \
        s1 = mfma16(qa[1][ks][1], k0v, s1);                                   \
        s1 = mfma16(qa[1][ks][0], k1v, s1);                                   \
        s1 = mfma16(qa[1][ks][1], k1v, s1);                                   \
        s1 = mfma16(qa[1][ks][0], k2v, s1);                                   \
        s1 = mfma16(qa[1][ks][2], k0v, s1);                                   \
      }                                                                       \
      if (DIAG) {                                                             \
        int jrow = (JT) * 64 + c * 16 + ln;                                   \
        for (int r = 0; r < 4; ++r) {                                         \
          if (jrow > ibase + q4 * 4 + r) s0[r] = -3e38f;                      \
          if (jrow > ibase + 16 + q4 * 4 + r) s1[r] = -3e38f;                 \
        }                                                                     \
      }                                                                       \
      for (int r = 0; r < 4; ++r) { p[0][c][r] = s0[r]; p[1][c][r] = s1[r]; } \
    }                                                                         \
    float alpha[2][4];                                                        \
    for (int mf = 0; mf < 2; ++mf)                                            \
      for (int r = 0; r < 4; ++r) {                                           \
        float tm = fmaxf(fmaxf(p[mf][0][r], p[mf][1][r]),                     \
                         fmaxf(p[mf][2][r], p[mf][3][r]));                    \
        for (int off = 8; off >= 1; off >>= 1)                                \
          tm = fmaxf(tm, __shfl_xor(tm, off, 16));                            \
        float mnew = fmaxf(m_r[mf][r], tm);                                   \
        alpha[mf][r] = exp2f(m_r[mf][r] - mnew);                              \
        m_r[mf][r] = mnew;                                                    \
      }                                                                       \
    for (int mf = 0; mf < 2; ++mf)                                            \
      for (int c = 0; c < 4; ++c)                                             \
        for (int r = 0; r < 4; ++r)                                           \
          p[mf][c][r] = exp2f(p[mf][c][r] - m_r[mf][r]);                      \
    for (int mf = 0; mf < 2; ++mf) {                                          \
      for (int c = 0; c < 4; ++c)                                             \
        for (int r = 0; r < 4; ++r) oacc[mf][c][r] *= alpha[mf][r];           \
      for (int r = 0; r < 4; ++r) lacc[mf][r] *= alpha[mf][r];                \
    }                                                                         \
    for (int mf = 0; mf < 2; ++mf) {                                          \
      __asm__ __volatile__("" ::: "memory");                                  \
      for (int c = 0; c < 4; ++c)                                             \
        for (int r = 0; r < 4; ++r)                                           \
          Plds[w][q4 * 4 + r][c * 16 + ln] =                                  \
              (unsigned short)(__builtin_bit_cast(unsigned, p[mf][c][r]) >> 16); \
      __asm__ __volatile__("" ::: "memory");                                  \
      for (int ks = 0; ks < 2; ++ks) {                                        \
        short8 pa = *(const short8*)&Plds[w][ln][ks * 32 + q4 * 8];           \
        for (int c = 0; c < 4; ++c) {                                         \
          int voff = ((c * 16 + ln) * 8 + ((ks * 4 + q4) ^ swz)) * 8;         \
          short8 vb = *(const short8*)&Vs[cur_][voff];                        \
          oacc[mf][c] = mfma16(pa, vb, oacc[mf][c]);                          \
        }                                                                     \
        lacc[mf] = mfma16(pa, ones, lacc[mf]);                                \
      }                                                                       \
      __asm__ __volatile__("" ::: "memory");                                  \
    }                                                                         \
  }

__global__ __launch_bounds__(256) void attn_kernel(
    const float* Qf, const unsigned short* K0, const unsigned short* K1,
    const unsigned short* K2, const unsigned short* VbT,
    unsigned short* Ob0, unsigned short* Ob1) {
  __shared__ unsigned short Ks[2][3][4096];
  __shared__ unsigned short Vs[2][4096];
  __shared__ unsigned short Plds[4][16][72];
  int tid = threadIdx.x;
  int w = tid >> 6, lane = tid & 63, q4 = lane >> 4, ln = lane & 15;
  int bidx = blockIdx.x;                       // 0..511
  int bh = ((bidx & 7) << 2) | ((bidx >> 3) & 3);   // XCD swizzle (bits 0..4)
  int u = bidx >> 5;                           // 0..15
  int tl = (u < 8) ? u : (23 - u);             // round1: 0..7, round2: 15..8
  const float* Qb = Qf + (size_t)bh * T_SEQ * HD;
  const unsigned short* Kb0 = K0 + (size_t)bh * T_SEQ * HD;
  const unsigned short* Kb1 = K1 + (size_t)bh * T_SEQ * HD;
  const unsigned short* Kb2 = K2 + (size_t)bh * T_SEQ * HD;
  const unsigned short* Vb = VbT + (size_t)bh * HD * T_SEQ;
  int b = bh >> 4, hh = bh & 15;
  float4v zero = {0.f, 0.f, 0.f, 0.f};
  short8 ones;
  for (int j = 0; j < 8; ++j) ones[j] = (short)(unsigned short)0x3F80;  // bf16 1.0

  int srow = tid >> 3, scs = tid & 7;
  int scd = scs ^ (srow & 7);
  int swz = ln & 7;

  int ibase = tl * 128 + w * 32;               // wave's first q-row
  int NT = 2 * tl + 2;                         // 64-col kv steps (last 2 diag)

  // Q fragments: 2 m-frags x 2 k-slices x 3 terms
  short8 qa[2][2][3];
  for (int mf = 0; mf < 2; ++mf) {
    const float* qp = Qb + (size_t)(ibase + mf * 16 + ln) * HD;
    for (int ks = 0; ks < 2; ++ks) {
      float f[8];
      *(float4v*)&f[0] = *(const float4v*)(qp + ks * 32 + q4 * 8);
      *(float4v*)&f[4] = *(const float4v*)(qp + ks * 32 + q4 * 8 + 4);
      for (int j = 0; j < 8; ++j) {
        unsigned short h0, h1, h2;
        split3(f[j], h0, h1, h2);
        qa[mf][ks][0][j] = (short)h0; qa[mf][ks][1][j] = (short)h1;
        qa[mf][ks][2][j] = (short)h2;
      }
    }
  }

  float m_r[2][4];
  for (int mf = 0; mf < 2; ++mf)
    for (int r = 0; r < 4; ++r) m_r[mf][r] = -3e38f;
  float4v lacc[2] = {zero, zero};
  float4v oacc[2][4];
  for (int mf = 0; mf < 2; ++mf)
    for (int c = 0; c < 4; ++c) oacc[mf][c] = zero;

  ATTN_STAGE(0, 0)
  for (int jt = 0; jt < NT - 2; ++jt) {
    __syncthreads();           // tile jt staged; reads of other buf drained
    ATTN_STAGE((jt + 1) & 1, (jt + 1) * 64)
    ATTN_STEP(jt, 0)
  }
  __syncthreads();
  ATTN_STAGE((NT - 1) & 1, (NT - 1) * 64)
  ATTN_STEP(NT - 2, 1)
  __syncthreads();
  ATTN_STEP(NT - 1, 1)

  for (int mf = 0; mf < 2; ++mf)
    for (int c = 0; c < 4; ++c)
      for (int r = 0; r < 4; ++r) {
        int i = ibase + mf * 16 + q4 * 4 + r;
        float val = oacc[mf][c][r] / lacc[mf][r];
        unsigned short h0, h1;
        split2(val, h0, h1);
        size_t o = ((size_t)(b * T_SEQ + i)) * D_MODEL + hh * 64 + c * 16 + ln;
        Ob0[o] = h0; Ob1[o] = h1;
      }
}
#undef ATTN_STAGE
#undef ATTN_STEP

// ---------------- output projection: LDS-staged, 3-term, fp32 out ----------------
__global__ __launch_bounds__(256) void proj_gemm(
    const unsigned short* A0, const unsigned short* A1,
    const unsigned short* P0, const unsigned short* P1, float* out) {
  __shared__ unsigned short SB[4 * 4096];
  int tid = threadIdx.x;
  int w = tid >> 6, lane = tid & 63, q4 = lane >> 4, ln = lane & 15;
  int wr = w >> 1, wc = w & 1;
  int n0g = blockIdx.x * 128;
  int m0 = blockIdx.y * 128;
  const unsigned short* Asrc[2] = {A0, A1};
  const unsigned short* Bsrc[2] = {P0, P1};

  float4v zero = {0.f, 0.f, 0.f, 0.f};
  float4v acc[4][4];
  for (int mt = 0; mt < 4; ++mt)
    for (int ct = 0; ct < 4; ++ct) acc[mt][ct] = zero;

  int srow = tid >> 2, kpart = tid & 3;
  int kswz = kpart ^ ((srow >> 1) & 3);     // inverse-swizzled source col-block
  int slot8 = (q4 ^ ((ln >> 1) & 3)) * 8;   // swizzled read slot (ushort offset)
  unsigned lds_off = (unsigned)tid * 16;

  for (int k0 = 0; k0 < D_MODEL; k0 += 32) {
    __syncthreads();
    for (int i = 0; i < 2; ++i) {
      size_t arow = (size_t)(m0 + srow + i * 64) * D_MODEL + k0 + kswz * 8;
      size_t brow = (size_t)(n0g + srow + i * 64) * D_MODEL + k0 + kswz * 8;
      for (int s = 0; s < 2; ++s) {
        stage16(Asrc[s] + arow, (unsigned short*)((char*)(SB + s * 4096) + lds_off + i * 4096));
        stage16(Bsrc[s] + brow, (unsigned short*)((char*)(SB + (2 + s) * 4096) + lds_off + i * 4096));
      }
    }
    __syncthreads();

    short8 af[4][2];
    for (int mt = 0; mt < 4; ++mt)
      for (int s = 0; s < 2; ++s)
        af[mt][s] = *(const short8*)(SB + s * 4096 + (wr * 64 + mt * 16 + ln) * 32 + slot8);
    for (int ct = 0; ct < 4; ++ct) {
      int brow = (wc * 64 + ct * 16 + ln) * 32 + slot8;
      short8 b0 = *(const short8*)(SB + 2 * 4096 + brow);
      short8 b1 = *(const short8*)(SB + 3 * 4096 + brow);
      for (int mt = 0; mt < 4; ++mt) {
        float4v a = acc[mt][ct];
        a = mfma16(af[mt][0], b0, a);
        a = mfma16(af[mt][1], b0, a);
        a = mfma16(af[mt][0], b1, a);
        acc[mt][ct] = a;
      }
    }
  }

  for (int mt = 0; mt < 4; ++mt)
    for (int ct = 0; ct < 4; ++ct)
      for (int r = 0; r < 4; ++r) {
        int gm = m0 + wr * 64 + mt * 16 + q4 * 4 + r;
        int col = n0g + wc * 64 + ct * 16 + ln;
        out[(size_t)gm * D_MODEL + col] = acc[mt][ct][r];
      }
}

extern "C" void kernel_launch(void* const* d_in, const int* in_sizes, int n_in,
                              void* d_out, int out_size, void* d_ws, size_t ws_size,
                              hipStream_t stream) {
  const float* x      = (const float*)d_in[0];
  const float* ln_w   = (const float*)d_in[1];
  const float* attn_w = (const float*)d_in[2];
  const float* proj_w = (const float*)d_in[3];
  const float* theta  = (const float*)d_in[4];
  float* out = (float*)d_out;

  char* ws = (char*)d_ws;
  const size_t SZY  = (size_t)4096 * 1024 * 2;        // 8,388,608
  const size_t SZW  = (size_t)3072 * 1024 * 2;        // 6,291,456
  const size_t SZW2 = (size_t)2048 * 1024 * 2;        // 4,194,304
  const size_t SZQ  = (size_t)2 * 16 * 2048 * 64 * 4; // 16,777,216 (fp32)
  const size_t SZK  = (size_t)2 * 16 * 2048 * 64 * 2; //  8,388,608 (bf16)

  unsigned short* y0 = (unsigned short*)(ws);
  unsigned short* y1 = (unsigned short*)(ws + SZY);
  unsigned short* y2 = (unsigned short*)(ws + 2 * SZY);
  unsigned short* W0 = (unsigned short*)(ws + 3 * SZY);
  unsigned short* W1 = (unsigned short*)(ws + 3 * SZY + SZW);
  unsigned short* W2 = (unsigned short*)(ws + 3 * SZY + 2 * SZW);
  float* Qf          = (float*)(ws + 3 * SZY + 2 * SZW + SZW2);
  unsigned short* K0 = (unsigned short*)(ws + 3 * SZY + 2 * SZW + SZW2 + SZQ);
  unsigned short* K1 = (unsigned short*)(ws + 3 * SZY + 2 * SZW + SZW2 + SZQ + SZK);
  float* E           = (float*)(ws + 3 * SZY + 2 * SZW + SZW2 + SZQ + 2 * SZK);
  float* Einv        = E + T_SEQ;
  // aliases into dead regions (y dead after qkv, then reused):
  unsigned short* Ob0 = y0;
  unsigned short* Ob1 = y1;
  unsigned short* PW0 = y2;
  unsigned short* PW1 = y2 + (size_t)1024 * 1024;
  // d_out scratch (16.78 MB): VbT low half, K2 high half; both dead before proj writes
  unsigned short* VbT = (unsigned short*)d_out;
  unsigned short* K2  = (unsigned short*)((char*)d_out + SZK);

  size_t needed = 3 * SZY + 2 * SZW + SZW2 + SZQ + 2 * SZK + 2 * T_SEQ * 4;  // 75,513,856
  if (ws_size < needed) return;  // loud failure: output stays zero

  static int lds_cfg = 0;
  if (!lds_cfg) {
    hipFuncSetAttribute((const void*)qkv_ring,
                        hipFuncAttributeMaxDynamicSharedMemorySize, 73728);
    lds_cfg = 1;
  }

  prep_kernel<<<dim3(5640), dim3(256), 0, stream>>>(x, ln_w, attn_w, theta,
                                                    y0, y1, y2, W0, W1, W2, E, Einv);
  qkv_ring<<<dim3(384), dim3(512), 73728, stream>>>(y0, y1, y2, W0, W1, W2, E, Einv,
                                                    Qf, K0, K1, K2, VbT);
  conv_pw<<<dim3(512), dim3(256), 0, stream>>>(proj_w, PW0, PW1);
  attn_kernel<<<dim3(512), dim3(256), 0, stream>>>(Qf, K0, K1, K2, VbT, Ob0, Ob1);
  proj_gemm<<<dim3(8, 32), dim3(256), 0, stream>>>(Ob0, Ob1, PW0, PW1, out);
}

// Round 7
// 367.464 us; speedup vs baseline: 1.1115x; 1.1115x over previous
//
#include <hip/hip_runtime.h>
#include <stdint.h>
#include <stddef.h>

typedef __attribute__((ext_vector_type(8))) short short8;
typedef __attribute__((ext_vector_type(4))) float float4v;

#define T_SEQ 2048
#define D_MODEL 1024
#define NH 16
#define HD 64

static __device__ __forceinline__ unsigned short f2bf(float f) {
  unsigned u = __builtin_bit_cast(unsigned, f);
  u += 0x7fffu + ((u >> 16) & 1u);
  return (unsigned short)(u >> 16);
}
static __device__ __forceinline__ float bf2f(unsigned short h) {
  unsigned u = ((unsigned)h) << 16;
  return __builtin_bit_cast(float, u);
}
static __device__ __forceinline__ float4v mfma16(short8 a, short8 b, float4v c) {
  return __builtin_amdgcn_mfma_f32_16x16x32_bf16(a, b, c, 0, 0, 0);
}
// fp32 -> 3 bf16 terms (sum reproduces f to ~2^-27 rel)
static __device__ __forceinline__ void split3(float f, unsigned short& h0,
                                              unsigned short& h1, unsigned short& h2) {
  h0 = f2bf(f);
  float r1 = f - bf2f(h0);
  h1 = f2bf(r1);
  float r2 = r1 - bf2f(h1);
  h2 = f2bf(r2);
}
// fp32 -> 2 bf16 terms (~2^-18 rel)
static __device__ __forceinline__ void split2(float f, unsigned short& h0, unsigned short& h1) {
  h0 = f2bf(f);
  h1 = f2bf(f - bf2f(h0));
}

// async global->LDS, 16 B per lane (global_load_lds_dwordx4); guarded fallback
static __device__ __forceinline__ void stage16(const unsigned short* g, unsigned short* l) {
#if __has_builtin(__builtin_amdgcn_global_load_lds)
  __builtin_amdgcn_global_load_lds(
      (const __attribute__((address_space(1))) unsigned int*)g,
      (__attribute__((address_space(3))) unsigned int*)l, 16, 0, 0);
#else
  *(short8*)l = *(const short8*)g;
#endif
}

// ---------------- prep: eta tables + LayerNorm split3 + attn_w split3 ----------------
__global__ __launch_bounds__(256) void prep_kernel(
    const float* x, const float* wgt, const float* attn_w, const float* theta,
    unsigned short* y0, unsigned short* y1, unsigned short* y2,
    unsigned short* W0, unsigned short* W1, unsigned short* W2,
    float* E, float* Einv) {
  __shared__ float rs[4], rq[4];
  int bx = blockIdx.x;
  int tid = threadIdx.x;
  if (bx < 4096) {                       // ---- LayerNorm rows ----
    int row = bx;
    const float* xr = x + (size_t)row * D_MODEL;
    float v[4];
    float sum = 0.f, ssq = 0.f;
    for (int it = 0; it < 4; ++it) {
      float f = xr[tid + 256 * it];
      v[it] = f;
      sum += f; ssq += f * f;
    }
    for (int off = 32; off >= 1; off >>= 1) {
      sum += __shfl_xor(sum, off, 64);
      ssq += __shfl_xor(ssq, off, 64);
    }
    int w = tid >> 6;
    if ((tid & 63) == 0) { rs[w] = sum; rq[w] = ssq; }
    __syncthreads();
    sum = rs[0] + rs[1] + rs[2] + rs[3];
    ssq = rq[0] + rq[1] + rq[2] + rq[3];
    float mu = sum * (1.0f / D_MODEL);
    float var = ssq * (1.0f / D_MODEL) - mu * mu;
    float rstd = rsqrtf(var + 1e-5f);
    for (int it = 0; it < 4; ++it) {
      int d = tid + 256 * it;
      float y = (v[it] - mu) * rstd * wgt[d];
      unsigned short h0, h1, h2;
      split3(y, h0, h1, h2);
      size_t o = (size_t)row * D_MODEL + d;
      y0[o] = h0; y1[o] = h1; y2[o] = h2;
    }
  } else if (bx < 5632) {                // ---- attn_w split3 ----
    size_t base = ((size_t)(bx - 4096) * 256 + tid) * 8;
    int row = (int)(base >> 10);
    short8 a, b, c;
    for (int j = 0; j < 8; ++j) {
      unsigned short h0, h1, h2;
      split3(attn_w[base + j], h0, h1, h2);
      a[j] = (short)h0; b[j] = (short)h1; c[j] = (short)h2;
    }
    *(short8*)(W0 + base) = a;
    *(short8*)(W1 + base) = b;
    if (row < 2048) *(short8*)(W2 + base) = c;
  } else {                               // ---- eta tables ----
    int i = (bx - 5632) * 256 + tid;
    if (i < T_SEQ) {
      float th = theta[0];
      float h = log1pf(expf(th));
      float t = 1.0f + h * (float)i;
      float eta = 3.0f * logf(t);
      eta = fminf(fmaxf(eta, -50.0f), 50.0f);
      E[i] = expf(eta);
      Einv[i] = expf(-eta);
    }
  }
}

// ---------------- proj_w (fp32) -> split2 ----------------
__global__ __launch_bounds__(256) void conv_pw(const float* src, unsigned short* P0,
                                               unsigned short* P1) {
  size_t base = ((size_t)blockIdx.x * 256 + threadIdx.x) * 8;
  short8 a, b;
  for (int j = 0; j < 8; ++j) {
    unsigned short h0, h1;
    split2(src[base + j], h0, h1);
    a[j] = (short)h0; b[j] = (short)h1;
  }
  *(short8*)(P0 + base) = a;
  *(short8*)(P1 + base) = b;
}

// =====================================================================
// QKV GEMM — BK=32, 3-buffer LDS ring, ONE 16-MFMA phase per k-tile.
// (round-5: 160 µs, MfmaUtil 35.5%; kept as-is)
// =====================================================================

#define RD_A(BUF, MF)                                                           \
  (*(const short8*)(lds_u + (BUF) * 12288 + (wm * 64 + (MF) * 16 + ln) * 32 +   \
                    slot8))
#define RD_B(BUF, NF)                                                           \
  (*(const short8*)(lds_u + (BUF) * 12288 + 8192 +                              \
                    (wn * 64 + (NF) * 16 + ln) * 32 + slot8))

#define STG(BUF, AP, BP, KI)                                                    \
  do {                                                                          \
    const unsigned short* ga = (AP) + (size_t)(m0 + srow) * 1024 + (KI) + kswz8; \
    stage16(ga, lds_u + (BUF) * 12288 + tid * 8);                               \
    stage16(ga + 128 * 1024, lds_u + (BUF) * 12288 + 4096 + tid * 8);           \
    stage16((BP) + (size_t)(brow0 + srow) * 1024 + (KI) + kswz8,                \
            lds_u + (BUF) * 12288 + 8192 + tid * 8);                            \
  } while (0)

#define ASEL(tb) ((tb) == 5 ? y2 : (((tb) & 1) ? y1 : y0))
#define BSEL(tb) (isV ? ((tb) < 2 ? W0 : W1)                                    \
                      : ((tb) < 2 ? W0 : ((tb) < 4 ? W1 : ((tb) == 4 ? W2 : W0))))

#define SBAR __builtin_amdgcn_s_barrier()
#define SCHED0 __builtin_amdgcn_sched_barrier(0)

#define PHASE(BUF, PBUF)                                                        \
  {                                                                             \
    short8 a0 = RD_A(BUF, 0), a1 = RD_A(BUF, 1);                                \
    short8 a2 = RD_A(BUF, 2), a3 = RD_A(BUF, 3);                                \
    short8 b0 = RD_B(BUF, 0), b1 = RD_B(BUF, 1);                                \
    short8 b2 = RD_B(BUF, 2), b3 = RD_B(BUF, 3);                                \
    bool pref = (t + 2 < NKT);                                                  \
    if (pref) {                                                                 \
      int tt = t + 2, tb = tt >> 5, ki = (tt & 31) << 5;                        \
      const unsigned short* Ap = ASEL(tb);                                      \
      const unsigned short* Bp = BSEL(tb);                                      \
      STG(PBUF, Ap, Bp, ki);                                                    \
    }                                                                           \
    SCHED0; SBAR;                                                               \
    asm volatile("s_waitcnt lgkmcnt(0)" ::: "memory");                          \
    SCHED0;                                                                     \
    __builtin_amdgcn_s_setprio(1);                                              \
    acc[0][0] = mfma16(a0, b0, acc[0][0]);                                      \
    acc[0][1] = mfma16(a0, b1, acc[0][1]);                                      \
    acc[0][2] = mfma16(a0, b2, acc[0][2]);                                      \
    acc[0][3] = mfma16(a0, b3, acc[0][3]);                                      \
    acc[1][0] = mfma16(a1, b0, acc[1][0]);                                      \
    acc[1][1] = mfma16(a1, b1, acc[1][1]);                                      \
    acc[1][2] = mfma16(a1, b2, acc[1][2]);                                      \
    acc[1][3] = mfma16(a1, b3, acc[1][3]);                                      \
    acc[2][0] = mfma16(a2, b0, acc[2][0]);                                      \
    acc[2][1] = mfma16(a2, b1, acc[2][1]);                                      \
    acc[2][2] = mfma16(a2, b2, acc[2][2]);                                      \
    acc[2][3] = mfma16(a2, b3, acc[2][3]);                                      \
    acc[3][0] = mfma16(a3, b0, acc[3][0]);                                      \
    acc[3][1] = mfma16(a3, b1, acc[3][1]);                                      \
    acc[3][2] = mfma16(a3, b2, acc[3][2]);                                      \
    acc[3][3] = mfma16(a3, b3, acc[3][3]);                                      \
    __builtin_amdgcn_s_setprio(0);                                              \
    SCHED0;                                                                     \
    if (pref) { asm volatile("s_waitcnt vmcnt(3)" ::: "memory"); }              \
    else      { asm volatile("s_waitcnt vmcnt(0)" ::: "memory"); }              \
    SBAR;                                                                       \
    ++t;                                                                        \
  }

__global__ __launch_bounds__(512, 4) void qkv_ring(
    const unsigned short* __restrict__ y0, const unsigned short* __restrict__ y1,
    const unsigned short* __restrict__ y2, const unsigned short* __restrict__ W0,
    const unsigned short* __restrict__ W1, const unsigned short* __restrict__ W2,
    const float* __restrict__ E, const float* __restrict__ Einv,
    float* __restrict__ Qf, unsigned short* __restrict__ K0,
    unsigned short* __restrict__ K1, unsigned short* __restrict__ K2,
    unsigned short* __restrict__ VbT) {
  extern __shared__ unsigned short lds_u[];  // 36864 ushorts = 72 KB
  int tid = threadIdx.x;
  int w = tid >> 6, lane = tid & 63, q4 = lane >> 4, ln = lane & 15;
  int wm = w >> 1, wn = w & 1;                    // wave grid 4x2, 64x64 each
  int slot8 = (q4 ^ ((ln >> 1) & 3)) * 8;         // HW-verified read swizzle
  int srow = tid >> 2;
  int kswz8 = ((tid & 3) ^ ((srow >> 1) & 3)) * 8;  // inverse source swizzle

  // grid: QK tiles first (bid<256), V tiles last; XCD swizzle (same-by adjacency)
  int bid = blockIdx.x, bx, by;
  if (bid < 256) {
    int wg = ((bid & 7) << 5) | (bid >> 3);
    by = wg >> 4; bx = wg & 15;
  } else {
    int vid = bid - 256;
    int wg = ((vid & 7) << 4) | (vid >> 3);
    by = wg >> 3; bx = 16 + (wg & 7);
  }
  int m0 = by * 256;
  bool isV = (bx >= 16);
  int NKT = isV ? 96 : 192;
  int brow0 = isV ? (2048 + (bx - 16) * 128) : bx * 128;

  float4v zero = {0.f, 0.f, 0.f, 0.f};
  float4v acc[4][4];
#pragma unroll
  for (int mf = 0; mf < 4; ++mf)
#pragma unroll
    for (int nf = 0; nf < 4; ++nf) acc[mf][nf] = zero;

  // prologue: stage tiles 0,1 into bufs 0,1 (6 loads); wait tile0 -> vmcnt(3)
  {
    const unsigned short* Ap = ASEL(0);
    const unsigned short* Bp = BSEL(0);
    STG(0, Ap, Bp, 0);
    STG(1, Ap, Bp, 32);
  }
  asm volatile("s_waitcnt vmcnt(3)" ::: "memory");
  SBAR;

  int t = 0;
  int nit = NKT / 3;
  for (int it = 0; it < nit; ++it) {
    PHASE(0, 2)
    PHASE(1, 0)
    PHASE(2, 1)
  }

  // ---------------- epilogue (loads drained: tail phases waited vmcnt(0)) ----
  int bi = m0 >> 11, m0g = m0 & 2047;
  if (bx < 8) {
    // Q: scale by E[t]*0.125*log2e, fp32, [bh][t][64]; two passes via LDS
    float* Ql = (float*)lds_u;  // [256][64]
    for (int g = 0; g < 2; ++g) {
      if (wn == g) {
#pragma unroll
        for (int mf = 0; mf < 4; ++mf)
#pragma unroll
          for (int nf = 0; nf < 4; ++nf)
#pragma unroll
            for (int r = 0; r < 4; ++r) {
              int rl = wm * 64 + mf * 16 + q4 * 4 + r;
              int tg = m0g + rl;
              Ql[rl * 64 + nf * 16 + ln] = acc[mf][nf][r] * (E[tg] * 0.1803368801f);
            }
      }
      __syncthreads();
      int h = bx * 2 + g;
      float* dst = Qf + ((size_t)(bi * NH + h) * T_SEQ + m0g) * HD;
      for (int itc = 0; itc < 8; ++itc) {
        int idx = itc * 512 + tid;
        *(float4v*)(dst + idx * 4) = *(const float4v*)(Ql + idx * 4);
      }
      __syncthreads();
    }
  } else if (bx < 16) {
    // K: scale by Einv[t], split3, [bh][t][64] x3; four (g,half) passes via LDS
    unsigned short* Kl = lds_u;  // [3][128][64] = 48 KB
    for (int g = 0; g < 2; ++g)
      for (int half = 0; half < 2; ++half) {
        if (wn == g && (wm >> 1) == half) {
#pragma unroll
          for (int mf = 0; mf < 4; ++mf)
#pragma unroll
            for (int nf = 0; nf < 4; ++nf)
#pragma unroll
              for (int r = 0; r < 4; ++r) {
                int rlh = (wm & 1) * 64 + mf * 16 + q4 * 4 + r;
                int tg = m0g + half * 128 + rlh;
                unsigned short h0, h1, h2;
                split3(acc[mf][nf][r] * Einv[tg], h0, h1, h2);
                int o = rlh * 64 + nf * 16 + ln;
                Kl[o] = h0; Kl[8192 + o] = h1; Kl[16384 + o] = h2;
              }
        }
        __syncthreads();
        int h = (bx - 8) * 2 + g;
        size_t base = ((size_t)(bi * NH + h) * T_SEQ + m0g + half * 128) * HD;
        for (int itc = 0; itc < 2; ++itc) {
          int idx = itc * 512 + tid;
          *(short8*)(K0 + base + idx * 8) = *(const short8*)(Kl + idx * 8);
          *(short8*)(K1 + base + idx * 8) = *(const short8*)(Kl + 8192 + idx * 8);
          *(short8*)(K2 + base + idx * 8) = *(const short8*)(Kl + 16384 + idx * 8);
        }
        __syncthreads();
      }
  } else {
    // V: bf16 truncate, transposed [bh][d][t]; two passes via LDS
    unsigned short* Vl = lds_u;  // [64][256] = 32 KB
    for (int g = 0; g < 2; ++g) {
      if (wn == g) {
#pragma unroll
        for (int mf = 0; mf < 4; ++mf)
#pragma unroll
          for (int nf = 0; nf < 4; ++nf)
#pragma unroll
            for (int r = 0; r < 4; ++r) {
              int rl = wm * 64 + mf * 16 + q4 * 4 + r;
              int d = nf * 16 + ln;
              Vl[d * 256 + rl] = f2bf(acc[mf][nf][r]);
            }
      }
      __syncthreads();
      int h = (bx - 16) * 2 + g;
      unsigned short* dst = VbT + (size_t)(bi * NH + h) * HD * T_SEQ + m0g;
      for (int itc = 0; itc < 4; ++itc) {
        int idx = itc * 512 + tid;
        int d = idx >> 5, c = idx & 31;
        *(short8*)(dst + (size_t)d * T_SEQ + c * 8) = *(const short8*)(Vl + d * 256 + c * 8);
      }
      __syncthreads();
    }
  }
}
#undef RD_A
#undef RD_B
#undef STG
#undef ASEL
#undef BSEL
#undef PHASE
#undef SBAR
#undef SCHED0

// ---------------- fused causal attention (round-5 balanced structure) ----------------
// Each block processes tiles px and 31-px SEQUENTIALLY -> every block exactly
// 33 steps (equal work), so the 2-blocks/CU co-residency never leaves a CU
// half-occupied (round-6 lesson: unequal co-resident blocks expose up to 30
// steps at half occupancy -> +30% on worst CUs).
#define ATTN_STAGE(BUF, J0)                                                   \
  for (int i_ = 0; i_ < 2; ++i_) {                                            \
    size_t go_ = (size_t)((J0) + srow + i_ * 32) * 64 + scd * 8;              \
    int lo_ = tid * 8 + i_ * 2048;                                            \
    stage16(Kb0 + go_, &Ks[BUF][0][lo_]);                                     \
    stage16(Kb1 + go_, &Ks[BUF][1][lo_]);                                     \
    stage16(Kb2 + go_, &Ks[BUF][2][lo_]);                                     \
    stage16(Vb + (size_t)(srow + i_ * 32) * T_SEQ + (J0) + scd * 8,           \
            &Vs[BUF][lo_]);                                                   \
  }

#define ATTN_STEP(JT, DIAG)                                                   \
  {                                                                           \
    const int cur_ = (JT) & 1;                                                \
    float p[4][4];                                                            \
    for (int c = 0; c < 4; ++c) {                                             \
      float4v s = zero;                                                       \
      for (int ks = 0; ks < 2; ++ks) {                                        \
        int koff = ((c * 16 + ln) * 8 + ((ks * 4 + q4) ^ swz)) * 8;           \
        short8 k0v = *(const short8*)&Ks[cur_][0][koff];                      \
        short8 k1v = *(const short8*)&Ks[cur_][1][koff];                      \
        short8 k2v = *(const short8*)&Ks[cur_][2][koff];                      \
        s = mfma16(qa[ks][0], k0v, s);                                        \
        s = mfma16(qa[ks][1], k0v, s);                                        \
        s = mfma16(qa[ks][0], k1v, s);                                        \
        s = mfma16(qa[ks][1], k1v, s);                                        \
        s = mfma16(qa[ks][0], k2v, s);                                        \
        s = mfma16(qa[ks][2], k0v, s);                                        \
      }                                                                       \
      if (DIAG) {                                                             \
        int jrow = (JT) * 64 + c * 16 + ln;                                   \
        for (int r = 0; r < 4; ++r)                                           \
          if (jrow > ibase + q4 * 4 + r) s[r] = -3e38f;                       \
      }                                                                       \
      for (int r = 0; r < 4; ++r) p[c][r] = s[r];                             \
    }                                                                         \
    float alpha[4], mnew[4];                                                  \
    for (int r = 0; r < 4; ++r) {                                             \
      float tm = fmaxf(fmaxf(p[0][r], p[1][r]), fmaxf(p[2][r], p[3][r]));     \
      for (int off = 8; off >= 1; off >>= 1)                                  \
        tm = fmaxf(tm, __shfl_xor(tm, off, 16));                              \
      mnew[r] = fmaxf(m_r[r], tm);                                            \
      alpha[r] = exp2f(m_r[r] - mnew[r]);                                     \
      m_r[r] = mnew[r];                                                       \
    }                                                                         \
    for (int c = 0; c < 4; ++c)                                               \
      for (int r = 0; r < 4; ++r) p[c][r] = exp2f(p[c][r] - mnew[r]);         \
    for (int c = 0; c < 4; ++c)                                               \
      for (int r = 0; r < 4; ++r) oacc[c][r] *= alpha[r];                     \
    for (int r = 0; r < 4; ++r) lacc[r] *= alpha[r];                          \
    __asm__ __volatile__("" ::: "memory");                                    \
    for (int c = 0; c < 4; ++c)                                               \
      for (int r = 0; r < 4; ++r)                                             \
        Plds[w][q4 * 4 + r][c * 16 + ln] =                                    \
            (unsigned short)(__builtin_bit_cast(unsigned, p[c][r]) >> 16);    \
    __asm__ __volatile__("" ::: "memory");                                    \
    for (int ks = 0; ks < 2; ++ks) {                                          \
      short8 pa = *(const short8*)&Plds[w][ln][ks * 32 + q4 * 8];             \
      for (int c = 0; c < 4; ++c) {                                           \
        int voff = ((c * 16 + ln) * 8 + ((ks * 4 + q4) ^ swz)) * 8;           \
        short8 vb = *(const short8*)&Vs[cur_][voff];                          \
        oacc[c] = mfma16(pa, vb, oacc[c]);                                    \
      }                                                                       \
      lacc = mfma16(pa, ones, lacc);                                          \
    }                                                                         \
    __asm__ __volatile__("" ::: "memory");                                    \
  }

__global__ __launch_bounds__(256) void attn_kernel(
    const float* Qf, const unsigned short* K0, const unsigned short* K1,
    const unsigned short* K2, const unsigned short* VbT,
    unsigned short* Ob0, unsigned short* Ob1) {
  __shared__ unsigned short Ks[2][3][4096];
  __shared__ unsigned short Vs[2][4096];
  __shared__ unsigned short Plds[4][16][72];
  int tid = threadIdx.x;
  int w = tid >> 6, lane = tid & 63, q4 = lane >> 4, ln = lane & 15;
  int bidx = blockIdx.x;                       // 0..511
  int bh = ((bidx & 7) << 2) | ((bidx >> 3) & 3);   // XCD swizzle
  int px = bidx >> 5;                          // 0..15 -> pair (px, 31-px)
  const float* Qb = Qf + (size_t)bh * T_SEQ * HD;
  const unsigned short* Kb0 = K0 + (size_t)bh * T_SEQ * HD;
  const unsigned short* Kb1 = K1 + (size_t)bh * T_SEQ * HD;
  const unsigned short* Kb2 = K2 + (size_t)bh * T_SEQ * HD;
  const unsigned short* Vb = VbT + (size_t)bh * HD * T_SEQ;
  int b = bh >> 4, hh = bh & 15;
  float4v zero = {0.f, 0.f, 0.f, 0.f};
  short8 ones;
  for (int j = 0; j < 8; ++j) ones[j] = (short)(unsigned short)0x3F80;  // bf16 1.0

  int srow = tid >> 3, scs = tid & 7;
  int scd = scs ^ (srow & 7);
  int swz = ln & 7;

  for (int half = 0; half < 2; ++half) {
    int qt = half ? (31 - px) : px;
    int q0 = qt * 64;
    int ibase = q0 + w * 16;

    short8 qa[2][3];
    {
      const float* qp = Qb + (size_t)(ibase + ln) * HD;
      for (int ks = 0; ks < 2; ++ks) {
        float f[8];
        *(float4v*)&f[0] = *(const float4v*)(qp + ks * 32 + q4 * 8);
        *(float4v*)&f[4] = *(const float4v*)(qp + ks * 32 + q4 * 8 + 4);
        for (int j = 0; j < 8; ++j) {
          unsigned short h0, h1, h2;
          split3(f[j], h0, h1, h2);
          qa[ks][0][j] = (short)h0; qa[ks][1][j] = (short)h1; qa[ks][2][j] = (short)h2;
        }
      }
    }

    float m_r[4] = {-3e38f, -3e38f, -3e38f, -3e38f};
    float4v lacc = zero;
    float4v oacc[4];
    for (int c = 0; c < 4; ++c) oacc[c] = zero;

    __syncthreads();           // previous half's reads drained
    ATTN_STAGE(0, 0)
    for (int jt = 0; jt < qt; ++jt) {
      __syncthreads();         // tile jt staged; reads of other buf drained
      ATTN_STAGE((jt + 1) & 1, (jt + 1) * 64)
      ATTN_STEP(jt, 0)
    }
    __syncthreads();           // diagonal tile staged
    ATTN_STEP(qt, 1)

    for (int c = 0; c < 4; ++c)
      for (int r = 0; r < 4; ++r) {
        int i = ibase + q4 * 4 + r;
        float val = oacc[c][r] / lacc[r];
        unsigned short h0, h1;
        split2(val, h0, h1);
        size_t o = ((size_t)(b * T_SEQ + i)) * D_MODEL + hh * 64 + c * 16 + ln;
        Ob0[o] = h0; Ob1[o] = h1;
      }
  }
}
#undef ATTN_STAGE
#undef ATTN_STEP

// ---------------- output projection: LDS-staged, 3-term, fp32 out ----------------
__global__ __launch_bounds__(256) void proj_gemm(
    const unsigned short* A0, const unsigned short* A1,
    const unsigned short* P0, const unsigned short* P1, float* out) {
  __shared__ unsigned short SB[4 * 4096];
  int tid = threadIdx.x;
  int w = tid >> 6, lane = tid & 63, q4 = lane >> 4, ln = lane & 15;
  int wr = w >> 1, wc = w & 1;
  int n0g = blockIdx.x * 128;
  int m0 = blockIdx.y * 128;
  const unsigned short* Asrc[2] = {A0, A1};
  const unsigned short* Bsrc[2] = {P0, P1};

  float4v zero = {0.f, 0.f, 0.f, 0.f};
  float4v acc[4][4];
  for (int mt = 0; mt < 4; ++mt)
    for (int ct = 0; ct < 4; ++ct) acc[mt][ct] = zero;

  int srow = tid >> 2, kpart = tid & 3;
  int kswz = kpart ^ ((srow >> 1) & 3);     // inverse-swizzled source col-block
  int slot8 = (q4 ^ ((ln >> 1) & 3)) * 8;   // swizzled read slot (ushort offset)
  unsigned lds_off = (unsigned)tid * 16;

  for (int k0 = 0; k0 < D_MODEL; k0 += 32) {
    __syncthreads();
    for (int i = 0; i < 2; ++i) {
      size_t arow = (size_t)(m0 + srow + i * 64) * D_MODEL + k0 + kswz * 8;
      size_t brow = (size_t)(n0g + srow + i * 64) * D_MODEL + k0 + kswz * 8;
      for (int s = 0; s < 2; ++s) {
        stage16(Asrc[s] + arow, (unsigned short*)((char*)(SB + s * 4096) + lds_off + i * 4096));
        stage16(Bsrc[s] + brow, (unsigned short*)((char*)(SB + (2 + s) * 4096) + lds_off + i * 4096));
      }
    }
    __syncthreads();

    short8 af[4][2];
    for (int mt = 0; mt < 4; ++mt)
      for (int s = 0; s < 2; ++s)
        af[mt][s] = *(const short8*)(SB + s * 4096 + (wr * 64 + mt * 16 + ln) * 32 + slot8);
    for (int ct = 0; ct < 4; ++ct) {
      int brow = (wc * 64 + ct * 16 + ln) * 32 + slot8;
      short8 b0 = *(const short8*)(SB + 2 * 4096 + brow);
      short8 b1 = *(const short8*)(SB + 3 * 4096 + brow);
      for (int mt = 0; mt < 4; ++mt) {
        float4v a = acc[mt][ct];
        a = mfma16(af[mt][0], b0, a);
        a = mfma16(af[mt][1], b0, a);
        a = mfma16(af[mt][0], b1, a);
        acc[mt][ct] = a;
      }
    }
  }

  for (int mt = 0; mt < 4; ++mt)
    for (int ct = 0; ct < 4; ++ct)
      for (int r = 0; r < 4; ++r) {
        int gm = m0 + wr * 64 + mt * 16 + q4 * 4 + r;
        int col = n0g + wc * 64 + ct * 16 + ln;
        out[(size_t)gm * D_MODEL + col] = acc[mt][ct][r];
      }
}

extern "C" void kernel_launch(void* const* d_in, const int* in_sizes, int n_in,
                              void* d_out, int out_size, void* d_ws, size_t ws_size,
                              hipStream_t stream) {
  const float* x      = (const float*)d_in[0];
  const float* ln_w   = (const float*)d_in[1];
  const float* attn_w = (const float*)d_in[2];
  const float* proj_w = (const float*)d_in[3];
  const float* theta  = (const float*)d_in[4];
  float* out = (float*)d_out;

  char* ws = (char*)d_ws;
  const size_t SZY  = (size_t)4096 * 1024 * 2;        // 8,388,608
  const size_t SZW  = (size_t)3072 * 1024 * 2;        // 6,291,456
  const size_t SZW2 = (size_t)2048 * 1024 * 2;        // 4,194,304
  const size_t SZQ  = (size_t)2 * 16 * 2048 * 64 * 4; // 16,777,216 (fp32)
  const size_t SZK  = (size_t)2 * 16 * 2048 * 64 * 2; //  8,388,608 (bf16)

  unsigned short* y0 = (unsigned short*)(ws);
  unsigned short* y1 = (unsigned short*)(ws + SZY);
  unsigned short* y2 = (unsigned short*)(ws + 2 * SZY);
  unsigned short* W0 = (unsigned short*)(ws + 3 * SZY);
  unsigned short* W1 = (unsigned short*)(ws + 3 * SZY + SZW);
  unsigned short* W2 = (unsigned short*)(ws + 3 * SZY + 2 * SZW);
  float* Qf          = (float*)(ws + 3 * SZY + 2 * SZW + SZW2);
  unsigned short* K0 = (unsigned short*)(ws + 3 * SZY + 2 * SZW + SZW2 + SZQ);
  unsigned short* K1 = (unsigned short*)(ws + 3 * SZY + 2 * SZW + SZW2 + SZQ + SZK);
  float* E           = (float*)(ws + 3 * SZY + 2 * SZW + SZW2 + SZQ + 2 * SZK);
  float* Einv        = E + T_SEQ;
  // aliases into dead regions (y dead after qkv, then reused):
  unsigned short* Ob0 = y0;
  unsigned short* Ob1 = y1;
  unsigned short* PW0 = y2;
  unsigned short* PW1 = y2 + (size_t)1024 * 1024;
  // d_out scratch (16.78 MB): VbT low half, K2 high half; both dead before proj writes
  unsigned short* VbT = (unsigned short*)d_out;
  unsigned short* K2  = (unsigned short*)((char*)d_out + SZK);

  size_t needed = 3 * SZY + 2 * SZW + SZW2 + SZQ + 2 * SZK + 2 * T_SEQ * 4;  // 75,513,856
  if (ws_size < needed) return;  // loud failure: output stays zero

  static int lds_cfg = 0;
  if (!lds_cfg) {
    hipFuncSetAttribute((const void*)qkv_ring,
                        hipFuncAttributeMaxDynamicSharedMemorySize, 73728);
    lds_cfg = 1;
  }

  prep_kernel<<<dim3(5640), dim3(256), 0, stream>>>(x, ln_w, attn_w, theta,
                                                    y0, y1, y2, W0, W1, W2, E, Einv);
  qkv_ring<<<dim3(384), dim3(512), 73728, stream>>>(y0, y1, y2, W0, W1, W2, E, Einv,
                                                    Qf, K0, K1, K2, VbT);
  conv_pw<<<dim3(512), dim3(256), 0, stream>>>(proj_w, PW0, PW1);
  attn_kernel<<<dim3(512), dim3(256), 0, stream>>>(Qf, K0, K1, K2, VbT, Ob0, Ob1);
  proj_gemm<<<dim3(8, 32), dim3(256), 0, stream>>>(Ob0, Ob1, PW0, PW1, out);
}